// Round 8
// baseline (149.901 us; speedup 1.0000x reference)
//
#include <hip/hip_runtime.h>
#include <hip/hip_bf16.h>
#include <stdint.h>

// Problem constants
#define Bq 8
#define Lq 2048
#define Dq 1024
#define Pq 4
#define Kq 4096          // D*P
#define LPAD 2056        // 3 zero rows + 2048 data + 5 slack, per batch
// GEMM tiling: 256x256, BK=64, 8 waves, 8-phase, B-persist,
// 32x32x16 MFMA (99.8%-of-peak shape vs 87% for 16x16x32)
#define BM 256
#define BN 256
#define BK 64

typedef __attribute__((ext_vector_type(8))) short short8;   // 8 bf16 (4 VGPRs)
typedef __attribute__((ext_vector_type(16))) float f32x16;

__device__ __forceinline__ unsigned short f2bf(float f) {
  unsigned u = __float_as_uint(f);
  u += 0x7FFFu + ((u >> 16) & 1u);   // round-to-nearest-even
  return (unsigned short)(u >> 16);
}

__device__ __forceinline__ void gload_lds16(const void* g, void* l) {
  __builtin_amdgcn_global_load_lds(
      (const __attribute__((address_space(1))) void*)g,
      (__attribute__((address_space(3))) void*)l, 16, 0, 0);
}

// ---- merged prep: blocks [0,8224) do xp, blocks [8224,10272) do Wp ----
__global__ void k_prep(const float* __restrict__ x, const float* __restrict__ W,
                       unsigned short* __restrict__ xp, unsigned short* __restrict__ Wp) {
  if (blockIdx.x < 8224u) {
    unsigned g = blockIdx.x * blockDim.x + threadIdx.x;
    unsigned base = g * 8;
    const unsigned total = (unsigned)Bq * LPAD * Dq;
    if (base >= total) return;
    unsigned t = base >> 10;            // b*LPAD + r
    unsigned b = t / LPAD;
    unsigned r = t - b * LPAD;
    unsigned d = base & 1023;
    short8 o;
    if (r >= 3 && r < 3 + Lq) {
      const float* s = x + ((size_t)b * Lq + (r - 3)) * Dq + d;
      float4 v0 = *(const float4*)(s);
      float4 v1 = *(const float4*)(s + 4);
      o[0] = (short)f2bf(v0.x); o[1] = (short)f2bf(v0.y);
      o[2] = (short)f2bf(v0.z); o[3] = (short)f2bf(v0.w);
      o[4] = (short)f2bf(v1.x); o[5] = (short)f2bf(v1.y);
      o[6] = (short)f2bf(v1.z); o[7] = (short)f2bf(v1.w);
    } else {
      o = (short8)0;
    }
    *(short8*)(xp + base) = o;
  } else {
    unsigned g = (blockIdx.x - 8224u) * blockDim.x + threadIdx.x;
    unsigned base = g * 8;
    unsigned d = base >> 12;
    unsigned rem = base & 4095;
    unsigned dp = rem >> 2;                               // even
    const float4* src = (const float4*)(W + base);
    float4 v0 = src[0];
    float4 v1 = src[1];
    float a0[4] = {v0.x, v0.y, v0.z, v0.w};
    float a1[4] = {v1.x, v1.y, v1.z, v1.w};
#pragma unroll
    for (int i = 0; i < 4; ++i) {
      unsigned packed = (unsigned)f2bf(a0[i]) | ((unsigned)f2bf(a1[i]) << 16);
      *(unsigned*)(Wp + (size_t)d * 4096 + (size_t)i * 1024 + dp) = packed;
    }
  }
}

// ================= 256x256 8-phase GEMM, B-persist, 32x32x16 MFMA ===========
// C[m][n] = sum_k A[m][k]*Wp[n][k] + bias[n],  A[m][i*1024+d'] = xp[b][l+3-i][d']
// LDS (128 KiB): A in [0,64K): [buf:32K][h:16K]; B in [64K,128K): same.
//   A-half h region row r (0..127): global A row m0 + (r>>6)*128 + h*64 + (r&63)
//   B-half h region row r (0..127): global B row n0 + (r>>5)*64 + h*32 + (r&31)
//   byte within 128B row: SWIZZLED  phys_c = log_c ^ ((r&7)<<4)
// 8 waves: wm = w>>2, wn = w&3. Quadrant order per tile: Q00,Q01,Q11,Q10.
// Frags: fa[2][4] (A-half: miH x ks), bX[4]=B-half0, bY[4]=B-half1 (persist).
// MFMA: 32x32x16 bf16; A-frag row=lane&31, k=(lane>>5)*8+e;
// C/D: col=lane&31, row=(reg&3)+8*(reg>>2)+4*(lane>>5)  [m74/m101 verified].
// Schedule (phases, barriers, vmcnt ledger) IDENTICAL to verified R5/R7.

#define VM6 asm volatile("s_waitcnt vmcnt(6)" ::: "memory")
#define VM4 asm volatile("s_waitcnt vmcnt(4)" ::: "memory")
#define VM0 asm volatile("s_waitcnt vmcnt(0)" ::: "memory")
#define BAR __builtin_amdgcn_s_barrier()

#define STAGE_A(buf, kt, h) do { \
    const unsigned scl_ = ((((unsigned)(bRow0 + (h) * 64 - ((kt) >> 4))) << 10) + (((unsigned)(kt) & 15u) << 6)) << 1; \
    _Pragma("unroll") for (int q_ = 0; q_ < 2; ++q_) \
      gload_lds16((const char*)xp + (thrA[q_] + scl_), \
                  lds + ((buf) << 15) + ((h) << 14) + (q_ << 13) + (tid << 4)); \
  } while (0)

#define STAGE_B(buf, kt, h) do { \
    const unsigned scl_ = ((((unsigned)(n0 + (h) * 32)) << 12) + ((unsigned)(kt) << 6)) << 1; \
    _Pragma("unroll") for (int q_ = 0; q_ < 2; ++q_) \
      gload_lds16((const char*)Wp + (thrB[q_] + scl_), \
                  lds + 65536 + ((buf) << 15) + ((h) << 14) + (q_ << 13) + (tid << 4)); \
  } while (0)

#define READ_A(dst, buf, h) do { \
    _Pragma("unroll") for (int mi = 0; mi < 2; ++mi) \
    _Pragma("unroll") for (int ks = 0; ks < 4; ++ks) \
      dst[mi][ks] = *(const short8*)(lds + (((buf) << 15) + ((h) << 14)) + aRC[mi][ks]); \
  } while (0)

#define READ_B(dst, buf, h) do { \
    _Pragma("unroll") for (int ks = 0; ks < 4; ++ks) \
      dst[ks] = *(const short8*)(lds + (((buf) << 15) + ((h) << 14)) + bRC[ks]); \
  } while (0)

#define MFMAQ(mh, nh, A, Bv) do { \
    __builtin_amdgcn_s_setprio(1); \
    _Pragma("unroll") for (int mi = 0; mi < 2; ++mi) \
    _Pragma("unroll") for (int ks = 0; ks < 4; ++ks) \
      acc[(mh) * 2 + mi][nh] = __builtin_amdgcn_mfma_f32_32x32x16_bf16( \
          A[mi][ks], Bv[ks], acc[(mh) * 2 + mi][nh], 0, 0, 0); \
    __builtin_amdgcn_s_setprio(0); \
  } while (0)

__global__ void __launch_bounds__(512, 2)
k_gemm(const unsigned short* __restrict__ xp,
       const unsigned short* __restrict__ Wp,
       const float* __restrict__ bias,
       float* __restrict__ out) {
  __shared__ __attribute__((aligned(16))) unsigned char lds[131072];

  const int tid  = threadIdx.x;
  const int lane = tid & 63;
  const int w    = tid >> 6;       // 0..7
  const int wm   = w >> 2;         // 0..1
  const int wn   = w & 3;          // 0..3

  // bijective XCD swizzle (256 blocks): each XCD gets a contiguous
  // 8-mtile x 4-ntile chunk -> A fetched once per XCD.
  const int bid = blockIdx.x;
  const int swz = (bid & 7) * 32 + (bid >> 3);
  const int m0 = (swz >> 2) * BM;
  const int n0 = (swz & 3) * BN;
  const int b  = m0 >> 11;
  const int l0 = m0 & 2047;
  const int bRow0 = b * LPAD + l0 + 3;           // SGPR

  // ---- staging geometry: per-thread u32 BYTE offsets (invariant part) ----
  const int sr0 = tid >> 3;                                  // 0..63
  const unsigned clog = ((unsigned)((tid & 7) ^ (sr0 & 7))) << 3;  // elem offset
  unsigned thrA[2], thrB[2];
  const unsigned nb0 = (((unsigned)sr0 >> 5) << 6) + ((unsigned)sr0 & 31);
#pragma unroll
  for (int q = 0; q < 2; ++q) {
    thrA[q] = ((((unsigned)(sr0 + q * 128)) << 10) + clog) << 1;   // bytes
    thrB[q] = (((nb0 + q * 128u) << 12) + clog) << 1;              // bytes
  }

  // ---- ds_read addresses: precomputed VGPRs, region via offset-imm ----
  // A: r = wm*64 + miH*32 + (lane&31); k-byte = (ks*32 + (lane>>5)*16) ^ swz(r)
  // B: r = wn*32 + (lane&31); same k-byte pattern; +65536 for B space
  int aRC[2][4], bRC[4];
  {
    const int kslot = (lane >> 5) << 4;
#pragma unroll
    for (int mi = 0; mi < 2; ++mi) {
      const int r = wm * 64 + mi * 32 + (lane & 31);
#pragma unroll
      for (int ks = 0; ks < 4; ++ks)
        aRC[mi][ks] = (r << 7) + ((ks * 32 + kslot) ^ ((r & 7) << 4));
    }
    const int rb = wn * 32 + (lane & 31);
#pragma unroll
    for (int ks = 0; ks < 4; ++ks)
      bRC[ks] = 65536 + (rb << 7) + ((ks * 32 + kslot) ^ ((rb & 7) << 4));
  }

  f32x16 acc[4][2] = {};
  short8 fa[2][4], bX[4], bY[4];

  // ---- prologue: stage tile0 fully + tile1 (Ah0,Bh1,Ah1) ----
  STAGE_A(0, 0, 0);
  STAGE_B(0, 0, 1);
  STAGE_A(0, 0, 1);
  STAGE_B(0, 0, 0);
  VM4;
  STAGE_A(1, 1, 0);
  STAGE_B(1, 1, 1);
  STAGE_A(1, 1, 1);
  VM6;                               // tile0 fully landed (per-wave)
  BAR;                               // all waves' tile0 landed

  // ---- main loop: 31 iters, tiles T=2it (buf0), U=2it+1 (buf1) ----
#pragma unroll 1
  for (int it = 0; it < 31; ++it) {
    const int T = it * 2;
    // ph1: Q00(T)=fa,bX   reads A0,B0,B1(T)  stage B0(U)
    READ_A(fa, 0, 0); READ_B(bX, 0, 0); READ_B(bY, 0, 1);
    STAGE_B(1, T + 1, 0);
    BAR; MFMAQ(0, 0, fa, bX); BAR;
    // ph2: Q01(T)=fa,bY   stage A0(T+2)
    STAGE_A(0, T + 2, 0);
    BAR; MFMAQ(0, 1, fa, bY); BAR;
    // ph3: Q11(T)=fa',bY  reads A1(T)        stage B1(T+2)
    READ_A(fa, 0, 1);
    STAGE_B(0, T + 2, 1);
    BAR; MFMAQ(1, 1, fa, bY); BAR;
    // ph4: Q10(T)=fa',bX  stage A1(T+2); VM6 -> tile U landed
    STAGE_A(0, T + 2, 1);
    VM6;
    BAR; MFMAQ(1, 0, fa, bX); BAR;
    // ph5: Q00(U)         reads A0,B0,B1(U)  stage B0(T+2)
    READ_A(fa, 1, 0); READ_B(bX, 1, 0); READ_B(bY, 1, 1);
    STAGE_B(0, T + 2, 0);
    BAR; MFMAQ(0, 0, fa, bX); BAR;
    // ph6: Q01(U)         stage A0(T+3)
    STAGE_A(1, T + 3, 0);
    BAR; MFMAQ(0, 1, fa, bY); BAR;
    // ph7: Q11(U)         reads A1(U)        stage B1(T+3)
    READ_A(fa, 1, 1);
    STAGE_B(1, T + 3, 1);
    BAR; MFMAQ(1, 1, fa, bY); BAR;
    // ph8: Q10(U)         stage A1(T+3); VM6 -> tile T+2 landed
    STAGE_A(1, T + 3, 1);
    VM6;
    BAR; MFMAQ(1, 0, fa, bX); BAR;
  }

  // ---- epilogue: tiles 62 (buf0), 63 (buf1) ----
  READ_A(fa, 0, 0); READ_B(bX, 0, 0); READ_B(bY, 0, 1);
  STAGE_B(1, 63, 0);                 // tile63 Bh0 (last missing piece)
  BAR; MFMAQ(0, 0, fa, bX); BAR;
  MFMAQ(0, 1, fa, bY);
  READ_A(fa, 0, 1);
  MFMAQ(1, 1, fa, bY);
  MFMAQ(1, 0, fa, bX);
  VM0;                               // tile63 landed (per-wave)
  BAR;                               // all waves' tile63 landed
  READ_A(fa, 1, 0); READ_B(bX, 1, 0); READ_B(bY, 1, 1);
  MFMAQ(0, 0, fa, bX);
  MFMAQ(0, 1, fa, bY);
  READ_A(fa, 1, 1);
  MFMAQ(1, 1, fa, bY);
  MFMAQ(1, 0, fa, bX);

  // ---- C write: col = lane&31, row = (reg&3) + 8*(reg>>2) + 4*(lane>>5) ----
#pragma unroll
  for (int ni = 0; ni < 2; ++ni) {
    const int col = n0 + wn * 64 + ni * 32 + (lane & 31);
    const float bv = bias[col];
#pragma unroll
    for (int mi = 0; mi < 4; ++mi) {
      const int rbase = m0 + wm * 128 + mi * 32 + ((lane >> 5) << 2);
#pragma unroll
      for (int g = 0; g < 4; ++g) {
#pragma unroll
        for (int j = 0; j < 4; ++j)
          out[(size_t)(rbase + 8 * g + j) * Dq + col] = acc[mi][ni][4 * g + j] + bv;
      }
    }
  }
}

// ---- slow-but-correct fallback if workspace is too small ----
__global__ void k_naive(const float* __restrict__ x, const float* __restrict__ W,
                        const float* __restrict__ bias, float* __restrict__ out) {
  size_t g = (size_t)blockIdx.x * blockDim.x + threadIdx.x;
  const size_t total = (size_t)Bq * Lq * Dq;
  if (g >= total) return;
  int d = (int)(g & 1023);
  int l = (int)((g >> 10) & 2047);
  int b = (int)(g >> 21);
  float s = bias[d];
  for (int i = 0; i < Pq; ++i) {
    if (l - i < 0) continue;
    const float* xr = x + ((size_t)b * Lq + (l - i)) * Dq;
    const float* wr = W + (size_t)d * Kq + i;
    float accv = 0.f;
    for (int dp = 0; dp < Dq; ++dp) accv += xr[dp] * wr[(size_t)dp * 4];
    s += accv;
  }
  out[g] = s;
}

extern "C" void kernel_launch(void* const* d_in, const int* in_sizes, int n_in,
                              void* d_out, int out_size, void* d_ws, size_t ws_size,
                              hipStream_t stream) {
  const float* x    = (const float*)d_in[0];
  const float* W    = (const float*)d_in[1];
  const float* bias = (const float*)d_in[2];
  float* out = (float*)d_out;

  const size_t WP_BYTES = (size_t)Dq * Kq * sizeof(unsigned short);        // 8 MiB
  const size_t XP_BYTES = (size_t)Bq * LPAD * Dq * sizeof(unsigned short); // ~33.7 MB

  if (ws_size < WP_BYTES + XP_BYTES) {
    const size_t total = (size_t)Bq * Lq * Dq;
    k_naive<<<(unsigned)((total + 255) / 256), 256, 0, stream>>>(x, W, bias, out);
    return;
  }

  unsigned short* Wp = (unsigned short*)d_ws;
  unsigned short* xp = (unsigned short*)((char*)d_ws + WP_BYTES);

  k_prep<<<10272, 256, 0, stream>>>(x, W, xp, Wp);
  k_gemm<<<dim3((Bq * Lq / BM) * (Dq / BN)), 512, 0, stream>>>(xp, Wp, bias, out);
}

// Round 9
// 128.992 us; speedup vs baseline: 1.1621x; 1.1621x over previous
//
#include <hip/hip_runtime.h>
#include <hip/hip_bf16.h>
#include <stdint.h>

// Problem constants
#define Bq 8
#define Lq 2048
#define Dq 1024
#define Pq 4
#define Kq 4096          // D*P
#define LPAD 2056        // 3 zero rows + 2048 data + 5 slack, per batch
// GEMM tiling: 256x256, BK=64, 8 waves, 2-phase/K-tile merged schedule,
// 16x16x32 MFMA (conflict-free swizzle pattern), kk-outer dep ordering.
#define BM 256
#define BN 256
#define BK 64

typedef __attribute__((ext_vector_type(8))) short short8;   // 8 bf16 (4 VGPRs)
typedef __attribute__((ext_vector_type(4))) float f32x4;

__device__ __forceinline__ unsigned short f2bf(float f) {
  unsigned u = __float_as_uint(f);
  u += 0x7FFFu + ((u >> 16) & 1u);   // round-to-nearest-even
  return (unsigned short)(u >> 16);
}

__device__ __forceinline__ void gload_lds16(const void* g, void* l) {
  __builtin_amdgcn_global_load_lds(
      (const __attribute__((address_space(1))) void*)g,
      (__attribute__((address_space(3))) void*)l, 16, 0, 0);
}

// ---- merged prep: blocks [0,8224) do xp, blocks [8224,10272) do Wp ----
__global__ void k_prep(const float* __restrict__ x, const float* __restrict__ W,
                       unsigned short* __restrict__ xp, unsigned short* __restrict__ Wp) {
  if (blockIdx.x < 8224u) {
    unsigned g = blockIdx.x * blockDim.x + threadIdx.x;
    unsigned base = g * 8;
    const unsigned total = (unsigned)Bq * LPAD * Dq;
    if (base >= total) return;
    unsigned t = base >> 10;            // b*LPAD + r
    unsigned b = t / LPAD;
    unsigned r = t - b * LPAD;
    unsigned d = base & 1023;
    short8 o;
    if (r >= 3 && r < 3 + Lq) {
      const float* s = x + ((size_t)b * Lq + (r - 3)) * Dq + d;
      float4 v0 = *(const float4*)(s);
      float4 v1 = *(const float4*)(s + 4);
      o[0] = (short)f2bf(v0.x); o[1] = (short)f2bf(v0.y);
      o[2] = (short)f2bf(v0.z); o[3] = (short)f2bf(v0.w);
      o[4] = (short)f2bf(v1.x); o[5] = (short)f2bf(v1.y);
      o[6] = (short)f2bf(v1.z); o[7] = (short)f2bf(v1.w);
    } else {
      o = (short8)0;
    }
    *(short8*)(xp + base) = o;
  } else {
    unsigned g = (blockIdx.x - 8224u) * blockDim.x + threadIdx.x;
    unsigned base = g * 8;
    unsigned d = base >> 12;
    unsigned rem = base & 4095;
    unsigned dp = rem >> 2;                               // even
    const float4* src = (const float4*)(W + base);
    float4 v0 = src[0];
    float4 v1 = src[1];
    float a0[4] = {v0.x, v0.y, v0.z, v0.w};
    float a1[4] = {v1.x, v1.y, v1.z, v1.w};
#pragma unroll
    for (int i = 0; i < 4; ++i) {
      unsigned packed = (unsigned)f2bf(a0[i]) | ((unsigned)f2bf(a1[i]) << 16);
      *(unsigned*)(Wp + (size_t)d * 4096 + (size_t)i * 1024 + dp) = packed;
    }
  }
}

// ============ 256x256 GEMM, 2-phase/K-tile, 1 barrier/phase ============
// C[m][n] = sum_k A[m][k]*Wp[n][k] + bias[n],  A[m][i*1024+d'] = xp[b][l+3-i][d']
// LDS (128 KiB): A in [0,64K): [buf:32K][h:16K]; B in [64K,128K): same.
//   byte within 128B row: SWIZZLED  phys_c = log_c ^ ((r&7)<<4)
// 8 waves: wm = w>>2, wn = w&3.
// Per K-tile T (buf = T&1):
//   phA: read A0,B0,B1(buf); stage A1(T+1, buf^1); 32 MFMA (Q00,Q01); VM8; BAR
//   phB: read A1(buf);       stage A0,B0,B1(T+2, buf); 32 MFMA (Q11,Q10); VM8; BAR
// Hazard proof: T+1 stages hit buf^1 while T reads buf (disjoint); T+2 stages
// hit regions whose T-reads completed last phase (barrier-separated). VM8
// ledger: every phase leaves exactly 8 gloads outstanding; the drained-oldest
// are precisely the region(s) the NEXT phase reads (verified incl. ends).
// MFMA kk-outer: dep distance 16 (no same-acc back-to-back stall).

#define VM8 asm volatile("s_waitcnt vmcnt(8)" ::: "memory")
#define VM2 asm volatile("s_waitcnt vmcnt(2)" ::: "memory")
#define VM0 asm volatile("s_waitcnt vmcnt(0)" ::: "memory")
#define BAR __builtin_amdgcn_s_barrier()
#define NOPS ((void)0)

#define STAGE_A(buf, kt, h) do { \
    const unsigned scl_ = ((((unsigned)(bRow0 + (h) * 64 - ((kt) >> 4))) << 10) + (((unsigned)(kt) & 15u) << 6)) << 1; \
    _Pragma("unroll") for (int q_ = 0; q_ < 2; ++q_) \
      gload_lds16((const char*)xp + (thrA[q_] + scl_), \
                  lds + ((buf) << 15) + ((h) << 14) + (q_ << 13) + (tid << 4)); \
  } while (0)

#define STAGE_B(buf, kt, h) do { \
    const unsigned scl_ = ((((unsigned)(n0 + (h) * 32)) << 12) + ((unsigned)(kt) << 6)) << 1; \
    _Pragma("unroll") for (int q_ = 0; q_ < 2; ++q_) \
      gload_lds16((const char*)Wp + (thrB[q_] + scl_), \
                  lds + 65536 + ((buf) << 15) + ((h) << 14) + (q_ << 13) + (tid << 4)); \
  } while (0)

#define READ_A(dst, buf, h) do { \
    _Pragma("unroll") for (int mi = 0; mi < 4; ++mi) \
    _Pragma("unroll") for (int kk = 0; kk < 2; ++kk) \
      dst[mi][kk] = *(const short8*)(lds + (((buf) << 15) + ((h) << 14)) + aRC[mi][kk]); \
  } while (0)

#define READ_B(dst, buf, h) do { \
    _Pragma("unroll") for (int ni = 0; ni < 2; ++ni) \
    _Pragma("unroll") for (int kk = 0; kk < 2; ++kk) \
      dst[ni][kk] = *(const short8*)(lds + (((buf) << 15) + ((h) << 14)) + bRC[ni][kk]); \
  } while (0)

// 32 MFMA covering quadrants (mh,0) and (mh,1), kk-outer (dep distance 16)
#define MFMA_PAIR(mh) do { \
    __builtin_amdgcn_s_setprio(1); \
    _Pragma("unroll") for (int kk = 0; kk < 2; ++kk) { \
      _Pragma("unroll") for (int mi = 0; mi < 4; ++mi) \
      _Pragma("unroll") for (int ni = 0; ni < 2; ++ni) \
        acc[(mh) * 4 + mi][ni] = __builtin_amdgcn_mfma_f32_16x16x32_bf16( \
            fa[mi][kk], bX[ni][kk], acc[(mh) * 4 + mi][ni], 0, 0, 0); \
      _Pragma("unroll") for (int mi = 0; mi < 4; ++mi) \
      _Pragma("unroll") for (int ni = 0; ni < 2; ++ni) \
        acc[(mh) * 4 + mi][2 + ni] = __builtin_amdgcn_mfma_f32_16x16x32_bf16( \
            fa[mi][kk], bY[ni][kk], acc[(mh) * 4 + mi][2 + ni], 0, 0, 0); \
    } \
    __builtin_amdgcn_s_setprio(0); \
  } while (0)

__global__ void __launch_bounds__(512, 2)
k_gemm(const unsigned short* __restrict__ xp,
       const unsigned short* __restrict__ Wp,
       const float* __restrict__ bias,
       float* __restrict__ out) {
  __shared__ __attribute__((aligned(16))) unsigned char lds[131072];

  const int tid  = threadIdx.x;
  const int lane = tid & 63;
  const int w    = tid >> 6;       // 0..7
  const int wm   = w >> 2;         // 0..1
  const int wn   = w & 3;          // 0..3

  // bijective XCD swizzle (256 blocks): each XCD gets a contiguous
  // 8-mtile x 4-ntile chunk -> A fetched once per XCD.
  const int bid = blockIdx.x;
  const int swz = (bid & 7) * 32 + (bid >> 3);
  const int m0 = (swz >> 2) * BM;
  const int n0 = (swz & 3) * BN;
  const int b  = m0 >> 11;
  const int l0 = m0 & 2047;
  const int bRow0 = b * LPAD + l0 + 3;           // SGPR

  // ---- staging geometry: per-thread u32 BYTE offsets (invariant part) ----
  const int sr0 = tid >> 3;                                  // 0..63
  const unsigned clog = ((unsigned)((tid & 7) ^ (sr0 & 7))) << 3;  // elem offset
  unsigned thrA[2], thrB[2];
  const unsigned nb0 = (((unsigned)sr0 >> 5) << 6) + ((unsigned)sr0 & 31);
#pragma unroll
  for (int q = 0; q < 2; ++q) {
    thrA[q] = ((((unsigned)(sr0 + q * 128)) << 10) + clog) << 1;   // bytes
    thrB[q] = (((nb0 + q * 128u) << 12) + clog) << 1;              // bytes
  }

  // ---- ds_read addresses: precomputed VGPRs, region via offset-imm ----
  int aRC[4][2], bRC[2][2];
  {
    int colByte[2];
#pragma unroll
    for (int kk = 0; kk < 2; ++kk)
      colByte[kk] = (kk * 64 + ((lane >> 4) << 4)) ^ ((lane & 7) << 4);
#pragma unroll
    for (int mi = 0; mi < 4; ++mi)
#pragma unroll
      for (int kk = 0; kk < 2; ++kk)
        aRC[mi][kk] = ((wm * 64 + mi * 16 + (lane & 15)) << 7) + colByte[kk];
#pragma unroll
    for (int ni = 0; ni < 2; ++ni)
#pragma unroll
      for (int kk = 0; kk < 2; ++kk)
        bRC[ni][kk] = 65536 + ((wn * 32 + ni * 16 + (lane & 15)) << 7) + colByte[kk];
  }

  f32x4 acc[8][4] = {};
  short8 fa[4][2], bX[2][2], bY[2][2];

  // ---- prologue: T0 full (A0,B0,B1,A1) + T1 (A0,B0,B1) = 14 gloads ----
  STAGE_A(0, 0, 0);
  STAGE_B(0, 0, 0);
  STAGE_B(0, 0, 1);
  STAGE_A(0, 0, 1);
  STAGE_A(1, 1, 0);
  STAGE_B(1, 1, 0);
  STAGE_B(1, 1, 1);
  VM8;                               // oldest 6 done = T0.{A0,B0,B1}
  BAR;

  // ---- main loop: 31 iters, tiles T=2it (buf0), U=T+1 (buf1) ----
#pragma unroll 1
  for (int it = 0; it < 31; ++it) {
    const int T = it * 2;
    // phA(T): reads A0,B0,B1(buf0); stage A1(T+1,buf1); MFMA Q00,Q01
    READ_A(fa, 0, 0); READ_B(bX, 0, 0); READ_B(bY, 0, 1);
    STAGE_A(1, T + 1, 1);
    MFMA_PAIR(0);
    VM8;                             // drains T0-slot A1 analog: prev tile's A1
    BAR;
    // phB(T): reads A1(buf0); stage A0,B0,B1(T+2,buf0); MFMA Q11,Q10
    READ_A(fa, 0, 1);
    STAGE_A(0, T + 2, 0); STAGE_B(0, T + 2, 0); STAGE_B(0, T + 2, 1);
    MFMA_PAIR(1);
    VM8;                             // drains (T+1).{A0,B0,B1}
    BAR;
    // phA(U): reads A0,B0,B1(buf1); stage A1(T+2,buf0); MFMA Q00,Q01
    READ_A(fa, 1, 0); READ_B(bX, 1, 0); READ_B(bY, 1, 1);
    STAGE_A(0, T + 2, 1);
    MFMA_PAIR(0);
    VM8;                             // drains (T+1).A1
    BAR;
    // phB(U): reads A1(buf1); stage A0,B0,B1(T+3,buf1); MFMA Q11,Q10
    READ_A(fa, 1, 1);
    STAGE_A(1, T + 3, 0); STAGE_B(1, T + 3, 0); STAGE_B(1, T + 3, 1);
    MFMA_PAIR(1);
    VM8;                             // drains (T+2).{A0,B0,B1}
    BAR;
  }

  // ---- epilogue: tiles 62 (buf0), 63 (buf1) ----
  // phA(62)
  READ_A(fa, 0, 0); READ_B(bX, 0, 0); READ_B(bY, 0, 1);
  STAGE_A(1, 63, 1);                 // last missing piece of tile 63
  MFMA_PAIR(0);
  VM8;
  BAR;
  // phB(62): no stage
  READ_A(fa, 0, 1);
  MFMA_PAIR(1);
  VM2;                               // 63.{A0,B0,B1} landed
  BAR;
  // phA(63)
  READ_A(fa, 1, 0); READ_B(bX, 1, 0); READ_B(bY, 1, 1);
  MFMA_PAIR(0);
  VM0;                               // 63.A1 landed
  BAR;
  // phB(63)
  READ_A(fa, 1, 1);
  MFMA_PAIR(1);

  // ---- C write: col = lane&15, row = (lane>>4)*4 + reg ----
#pragma unroll
  for (int nig = 0; nig < 4; ++nig) {
    const int col = n0 + wn * 64 + nig * 16 + (lane & 15);
    const float bv = bias[col];
#pragma unroll
    for (int mig = 0; mig < 8; ++mig) {
      const int row0 = m0 + wm * 128 + mig * 16 + ((lane >> 4) << 2);
#pragma unroll
      for (int t2 = 0; t2 < 4; ++t2)
        out[(size_t)(row0 + t2) * Dq + col] = acc[mig][nig][t2] + bv;
    }
  }
}

// ---- slow-but-correct fallback if workspace is too small ----
__global__ void k_naive(const float* __restrict__ x, const float* __restrict__ W,
                        const float* __restrict__ bias, float* __restrict__ out) {
  size_t g = (size_t)blockIdx.x * blockDim.x + threadIdx.x;
  const size_t total = (size_t)Bq * Lq * Dq;
  if (g >= total) return;
  int d = (int)(g & 1023);
  int l = (int)((g >> 10) & 2047);
  int b = (int)(g >> 21);
  float s = bias[d];
  for (int i = 0; i < Pq; ++i) {
    if (l - i < 0) continue;
    const float* xr = x + ((size_t)b * Lq + (l - i)) * Dq;
    const float* wr = W + (size_t)d * Kq + i;
    float accv = 0.f;
    for (int dp = 0; dp < Dq; ++dp) accv += xr[dp] * wr[(size_t)dp * 4];
    s += accv;
  }
  out[g] = s;
}

extern "C" void kernel_launch(void* const* d_in, const int* in_sizes, int n_in,
                              void* d_out, int out_size, void* d_ws, size_t ws_size,
                              hipStream_t stream) {
  const float* x    = (const float*)d_in[0];
  const float* W    = (const float*)d_in[1];
  const float* bias = (const float*)d_in[2];
  float* out = (float*)d_out;

  const size_t WP_BYTES = (size_t)Dq * Kq * sizeof(unsigned short);        // 8 MiB
  const size_t XP_BYTES = (size_t)Bq * LPAD * Dq * sizeof(unsigned short); // ~33.7 MB

  if (ws_size < WP_BYTES + XP_BYTES) {
    const size_t total = (size_t)Bq * Lq * Dq;
    k_naive<<<(unsigned)((total + 255) / 256), 256, 0, stream>>>(x, W, bias, out);
    return;
  }

  unsigned short* Wp = (unsigned short*)d_ws;
  unsigned short* xp = (unsigned short*)((char*)d_ws + WP_BYTES);

  k_prep<<<10272, 256, 0, stream>>>(x, W, xp, Wp);
  k_gemm<<<dim3((Bq * Lq / BM) * (Dq / BN)), 512, 0, stream>>>(xp, Wp, bias, out);
}